// Round 15
// baseline (437.202 us; speedup 1.0000x reference)
//
#include <hip/hip_runtime.h>
#include <stdint.h>

#define T_TOK 4096
#define DDIM  1024
#define HDIM  4096
#define NEXP  8
#define MAXT256 40   // sum_e ceil(cnt_e/256) <= 8192/256 + 8

typedef short s16x8  __attribute__((ext_vector_type(8)));
typedef short s16x4  __attribute__((ext_vector_type(4)));
typedef float f32x4t __attribute__((ext_vector_type(4)));

#define GLOAD16(gp, lp) __builtin_amdgcn_global_load_lds( \
    (const __attribute__((address_space(1))) unsigned int*)(gp), \
    (__attribute__((address_space(3))) unsigned int*)(lp), 16, 0, 0)
#define SB0 __builtin_amdgcn_sched_barrier(0)

__device__ __forceinline__ unsigned short f2b(float f){
  unsigned int u = __float_as_uint(f);
  u += 0x7fffu + ((u >> 16) & 1u);   // RNE
  return (unsigned short)(u >> 16);
}

// BK=32 rows are 64 B (4 x 16B slots). Swizzle: slot ^= (row>>1)&3 (R8/R9/R12-verified pair).
__device__ __forceinline__ s16x8 lds_frag(const unsigned short* base, int row, int colElem){
  int byte = row*64 + ((colElem*2) ^ (((row >> 1) & 3) << 4));
  return *(const s16x8*)((const char*)base + byte);
}

// ---------------- gate + x->bf16 conversion (fused) ----------------
__global__ void gate_kernel(const float* __restrict__ x, const float* __restrict__ Wg,
                            const float* __restrict__ bg,
                            int* __restrict__ topk_e, float* __restrict__ topk_w,
                            unsigned short* __restrict__ xb){
  const int t = blockIdx.x;
  const int lane = threadIdx.x;
  const float* xr = x + (size_t)t * DDIM;
  unsigned short* xbr = xb + (size_t)t * DDIM;
  float acc[NEXP];
  #pragma unroll
  for (int e = 0; e < NEXP; ++e) acc[e] = 0.f;
  #pragma unroll 4
  for (int it = 0; it < DDIM/64; ++it){
    int i = it*64 + lane;
    float xi = xr[i];
    xbr[i] = f2b(xi);                      // fused conv_x
    const float4* wr = (const float4*)(Wg + (size_t)i * NEXP);
    float4 w0 = wr[0], w1 = wr[1];
    acc[0] += xi*w0.x; acc[1] += xi*w0.y; acc[2] += xi*w0.z; acc[3] += xi*w0.w;
    acc[4] += xi*w1.x; acc[5] += xi*w1.y; acc[6] += xi*w1.z; acc[7] += xi*w1.w;
  }
  #pragma unroll
  for (int e = 0; e < NEXP; ++e){
    float v = acc[e];
    #pragma unroll
    for (int off = 32; off > 0; off >>= 1) v += __shfl_xor(v, off, 64);
    acc[e] = v;
  }
  if (lane == 0){
    float l[NEXP], m = -1e30f;
    #pragma unroll
    for (int e = 0; e < NEXP; ++e){ l[e] = acc[e] + bg[e]; m = fmaxf(m, l[e]); }
    float p[NEXP], s = 0.f;
    #pragma unroll
    for (int e = 0; e < NEXP; ++e){ p[e] = expf(l[e] - m); s += p[e]; }
    float inv = 1.f / s;
    int a1 = 0; float v1 = -1.f;
    #pragma unroll
    for (int e = 0; e < NEXP; ++e){ p[e] *= inv; if (p[e] > v1){ v1 = p[e]; a1 = e; } }
    int a2 = -1; float v2 = -1.f;
    #pragma unroll
    for (int e = 0; e < NEXP; ++e){ if (e == a1) continue; if (p[e] > v2){ v2 = p[e]; a2 = e; } }
    topk_e[2*t]   = a1; topk_w[2*t]   = v1;
    topk_e[2*t+1] = a2; topk_w[2*t+1] = v2;
  }
}

// ---------------- routing: per-expert ordered compaction ----------------
__global__ void route_count(const int* __restrict__ topk_e, const float* __restrict__ topk_w,
                            int* __restrict__ expertList, float* __restrict__ pairW,
                            int* __restrict__ counts){
  const int e = blockIdx.x;
  const int tid = threadIdx.x;
  __shared__ int pfx[256];
  __shared__ int base_s;
  if (tid == 0) base_s = 0;
  __syncthreads();
  for (int c = 0; c < T_TOK/256; ++c){
    int t = c*256 + tid;
    int e0 = topk_e[2*t], e1 = topk_e[2*t+1];
    int sel = 0; float w = 0.f;
    if (e0 == e){ sel = 1; w = topk_w[2*t]; }
    else if (e1 == e){ sel = 1; w = topk_w[2*t+1]; }
    pfx[tid] = sel;
    __syncthreads();
    for (int off = 1; off < 256; off <<= 1){
      int v = (tid >= off) ? pfx[tid - off] : 0;
      __syncthreads();
      pfx[tid] += v;
      __syncthreads();
    }
    if (sel){
      int pos = base_s + pfx[tid] - 1;
      expertList[e*T_TOK + pos] = t;
      pairW[e*T_TOK + pos] = w;
    }
    __syncthreads();
    if (tid == 0) base_s += pfx[255];
    __syncthreads();
  }
  if (tid == 0) counts[e] = base_s;
}

__global__ void plan_kernel(const int* __restrict__ counts, int* __restrict__ nTiles,
                            int* __restrict__ tileExpert, int* __restrict__ tileStart){
  if (blockIdx.x != 0 || threadIdx.x != 0) return;
  int nt = 0;
  for (int e = 0; e < NEXP; ++e){
    int c = counts[e];
    int tcount = (c + 255) >> 8;
    for (int i = 0; i < tcount; ++i){ tileExpert[nt] = e; tileStart[nt] = i*256; ++nt; }
  }
  *nTiles = nt;
}

// ---------------- pre-pass: W [E][K][N] fp32 -> Wt [E][N][K] bf16 ----------------
__global__ __launch_bounds__(256)
void transpose_w(const float* __restrict__ W, unsigned short* __restrict__ Wt,
                 int K, int N){
  const int e = blockIdx.z;
  const float* Wb = W + (size_t)e*K*N;
  unsigned short* Wtb = Wt + (size_t)e*K*N;
  const int n0 = blockIdx.x*64, k0 = blockIdx.y*64;
  __shared__ unsigned short t[64][72];
  const int r  = threadIdx.x >> 4;
  const int c4 = (threadIdx.x & 15) * 4;
  #pragma unroll
  for (int i = 0; i < 4; ++i){
    int k = r + i*16;
    float4 v = *(const float4*)(Wb + (size_t)(k0+k)*N + n0 + c4);
    t[c4+0][k] = f2b(v.x); t[c4+1][k] = f2b(v.y);
    t[c4+2][k] = f2b(v.z); t[c4+3][k] = f2b(v.w);
  }
  __syncthreads();
  const int kk = (threadIdx.x & 7) * 8;
  #pragma unroll
  for (int i = 0; i < 2; ++i){
    int n = (threadIdx.x >> 3) + i*32;
    s16x8 v;
    #pragma unroll
    for (int j = 0; j < 8; ++j) v[j] = (short)t[n][kk+j];
    *(s16x8*)(Wtb + (size_t)(n0+n)*K + k0 + kk) = v;
  }
}

// ------- grouped GEMM: 256x128 block, 4 waves (2Mx2N of 128x64), BK=32, dbuf -------
// R15 vs R12: DOUBLED per-wave M-tile (acc[8][4]) -> LDS-read bytes per FLOP drop
// 8 -> 6 B/MFMA and per-CU read-cycles per FLOP halve (fewer waves, more work each).
template<int LAYER, int KS>
__global__ __launch_bounds__(256, 2)
void moe_gemm(const unsigned short* __restrict__ Abf,
              const unsigned short* __restrict__ Wt,
              const float* __restrict__ bias,
              const int* __restrict__ nTilesPtr,
              const int* __restrict__ tileExpert,
              const int* __restrict__ tileStart,
              const int* __restrict__ counts,
              const int* __restrict__ expertList,
              const float* __restrict__ pairW,
              unsigned short* __restrict__ Hout,
              float* __restrict__ out)
{
  constexpr int KD = (LAYER == 1) ? DDIM : HDIM;
  constexpr int ND = (LAYER == 1) ? HDIM : DDIM;
  constexpr int NB = ND / 128;
  constexpr int NTfull = KD / 32;

  // bijective chunked XCD swizzle; n0-fastest decode (A panel shared on an XCD)
  const int nwg = gridDim.x;
  const int b   = blockIdx.x;
  const int q8 = nwg >> 3, r8 = nwg & 7;
  const int xcd = b & 7, ii = b >> 3;
  const int lin = (xcd < r8 ? xcd*(q8+1) : r8*(q8+1) + (xcd-r8)*q8) + ii;
  const int tile = lin / NB;
  const int n0   = (lin % NB) * 128;
  const int kz   = blockIdx.y;

  if (tile >= *nTilesPtr) return;
  const int e   = tileExpert[tile];
  const int ts  = tileStart[tile];
  const int cnt = counts[e];
  const int tid  = threadIdx.x;
  const int lane = tid & 63;
  const int wave = tid >> 6;         // 0..3
  const int wm = (wave >> 1) * 128;  // M half (128 rows per wave)
  const int wn = (wave & 1) * 64;    // N half (64 cols per wave)

  __shared__ __align__(16) unsigned short As[2][256][32];   // 32 KB
  __shared__ __align__(16) unsigned short Bs[2][128][32];   // 16 KB
  __shared__ int   tokenBuf[256];
  __shared__ float wBuf[256];

  {
    int pos = ts + tid;
    int tok = 0; float w = 0.f;
    if (pos < cnt){ tok = expertList[e*T_TOK + pos]; w = pairW[e*T_TOK + pos]; }
    tokenBuf[tid] = tok; wBuf[tid] = w;
  }
  __syncthreads();

  // staging: linear LDS dest; PRE-SWIZZLED global source (involution w/ read side)
  const int srow = tid >> 2;                                  // 0..63
  const int slot = (tid & 3) ^ ((tid >> 3) & 3);              // (row>>1)&3 == (tid>>3)&3
  const int koff = slot * 8;                                  // element offset in 32-wide row
  const unsigned short* gA[4];
  const unsigned short* gB[2];
  #pragma unroll
  for (int g = 0; g < 4; ++g){
    const int row = g*64 + srow;
    if (LAYER == 1) gA[g] = Abf + (size_t)tokenBuf[row]*DDIM + koff;
    else            gA[g] = Abf + (size_t)(tile*256 + row)*HDIM + koff;
  }
  #pragma unroll
  for (int g = 0; g < 2; ++g)
    gB[g] = Wt + ((size_t)e*ND + n0 + g*64 + srow)*KD + koff;

  auto STAGE = [&](int buf, int ko){
    unsigned short* la = &As[buf][0][0] + wave*512;   // wave-uniform base + lane*16B
    unsigned short* lb = &Bs[buf][0][0] + wave*512;
    #pragma unroll
    for (int g = 0; g < 4; ++g) GLOAD16(gA[g] + ko, la + g*2048);
    #pragma unroll
    for (int g = 0; g < 2; ++g) GLOAD16(gB[g] + ko, lb + g*2048);
  };

  f32x4t acc[8][4] = {};
  const int fr = lane & 15;
  const int fq = lane >> 4;

  const int kt0 = (kz * NTfull) / KS;
  const int kt1 = ((kz + 1) * NTfull) / KS;
  const int NTl = kt1 - kt0;

  // prologue: issue first tile's 6 loads (wait handled at loop top)
  STAGE(0, kt0*32);

  int cur = 0;
  for (int t = 0; t < NTl; ++t){
    // issue next tile's 6 loads, then wait ONLY for current tile's 6
    if (t + 1 < NTl){
      STAGE(cur ^ 1, (kt0 + t + 1)*32);
      SB0; asm volatile("s_waitcnt vmcnt(6)" ::: "memory");
    } else {
      SB0; asm volatile("s_waitcnt vmcnt(0)" ::: "memory");
    }
    __builtin_amdgcn_s_barrier();       // all waves' cur fills visible
    SB0;

    const unsigned short* Ab = &As[cur][0][0];
    const unsigned short* Bb = &Bs[cur][0][0];
    s16x8 bfr[4], afr[8];
    #pragma unroll
    for (int nf = 0; nf < 4; ++nf) bfr[nf] = lds_frag(Bb, wn + nf*16 + fr, fq*8);
    #pragma unroll
    for (int mf = 0; mf < 8; ++mf) afr[mf] = lds_frag(Ab, wm + mf*16 + fr, fq*8);
    #pragma unroll
    for (int mf = 0; mf < 8; ++mf)
      #pragma unroll
      for (int nf = 0; nf < 4; ++nf)
        acc[mf][nf] = __builtin_amdgcn_mfma_f32_16x16x32_bf16(afr[mf], bfr[nf], acc[mf][nf], 0, 0, 0);

    SB0;
    __builtin_amdgcn_s_barrier();       // readers done -> buf cur overwritable next iter
    SB0;
    cur ^= 1;
  }

  // ---- epilogue ----
  const int rbase = wm + fq*4;
  const int cbase = wn + fr;
  if (LAYER == 1){
    #pragma unroll
    for (int mf = 0; mf < 8; ++mf){
      #pragma unroll
      for (int nf = 0; nf < 4; ++nf){
        int c = cbase + nf*16;
        float bsv = bias[e*HDIM + n0 + c];
        #pragma unroll
        for (int j = 0; j < 4; ++j){
          int rr = rbase + mf*16 + j;
          float v = fmaxf(acc[mf][nf][j] + bsv, 0.f);
          __builtin_nontemporal_store((unsigned short)f2b(v),
              &Hout[(size_t)(tile*256 + rr)*HDIM + n0 + c]);
        }
      }
    }
  } else {
    #pragma unroll
    for (int mf = 0; mf < 8; ++mf){
      #pragma unroll
      for (int j = 0; j < 4; ++j){
        int rr = rbase + mf*16 + j;
        if (ts + rr < cnt){
          int tok = tokenBuf[rr];
          float w = wBuf[rr];
          #pragma unroll
          for (int nf = 0; nf < 4; ++nf){
            int c = cbase + nf*16;
            float v = acc[mf][nf][j];
            if (kz == 0) v += bias[e*DDIM + n0 + c];
            atomicAdd(out + (size_t)tok*DDIM + n0 + c, w * v);
          }
        }
      }
    }
  }
}

extern "C" void kernel_launch(void* const* d_in, const int* in_sizes, int n_in,
                              void* d_out, int out_size, void* d_ws, size_t ws_size,
                              hipStream_t stream){
  const float* x  = (const float*)d_in[0];
  const float* Wg = (const float*)d_in[1];
  const float* bg = (const float*)d_in[2];
  const float* W1 = (const float*)d_in[3];
  const float* b1 = (const float*)d_in[4];
  const float* W2 = (const float*)d_in[5];
  const float* b2 = (const float*)d_in[6];
  float* out = (float*)d_out;

  char* p = (char*)d_ws;
  int*   topk_e     = (int*)p;   p += (size_t)T_TOK*2*sizeof(int);
  float* topk_w     = (float*)p; p += (size_t)T_TOK*2*sizeof(float);
  int*   counts     = (int*)p;   p += 8*sizeof(int);
  int*   nTiles     = (int*)p;   p += 8*sizeof(int);
  int*   tileExpert = (int*)p;   p += 128*sizeof(int);
  int*   tileStart  = (int*)p;   p += 128*sizeof(int);
  int*   expertList = (int*)p;   p += (size_t)NEXP*T_TOK*sizeof(int);
  float* pairW      = (float*)p; p += (size_t)NEXP*T_TOK*sizeof(float);
  p = (char*)(((uintptr_t)p + 255) & ~(uintptr_t)255);
  unsigned short* xb = (unsigned short*)p;    // 8 MB
  p += (size_t)T_TOK*DDIM*sizeof(unsigned short);
  p = (char*)(((uintptr_t)p + 255) & ~(uintptr_t)255);
  unsigned short* Wtbuf = (unsigned short*)p; // 67 MB (W1t, then W2t)
  p += (size_t)NEXP*DDIM*HDIM*sizeof(unsigned short);
  p = (char*)(((uintptr_t)p + 255) & ~(uintptr_t)255);
  unsigned short* Hact = (unsigned short*)p;  // 40*256*4096*2 = 84 MB

  hipMemsetAsync(d_out, 0, (size_t)T_TOK*DDIM*sizeof(float), stream);
  gate_kernel<<<T_TOK, 64, 0, stream>>>(x, Wg, bg, topk_e, topk_w, xb);
  route_count<<<NEXP, 256, 0, stream>>>(topk_e, topk_w, expertList, pairW, counts);
  plan_kernel<<<1, 1, 0, stream>>>(counts, nTiles, tileExpert, tileStart);

  transpose_w<<<dim3(HDIM/64, DDIM/64, NEXP), 256, 0, stream>>>(W1, Wtbuf, DDIM, HDIM);
  moe_gemm<1,1><<<dim3(MAXT256*(HDIM/128), 1), 256, 0, stream>>>(
      xb, Wtbuf, b1, nTiles, tileExpert, tileStart, counts, expertList, pairW, Hact, nullptr);

  transpose_w<<<dim3(DDIM/64, HDIM/64, NEXP), 256, 0, stream>>>(W2, Wtbuf, HDIM, DDIM);
  moe_gemm<2,3><<<dim3(MAXT256*(DDIM/128), 3), 256, 0, stream>>>(
      Hact, Wtbuf, b2, nTiles, tileExpert, tileStart, counts, expertList, pairW, nullptr, out);
}

// Round 16
// 406.489 us; speedup vs baseline: 1.0756x; 1.0756x over previous
//
#include <hip/hip_runtime.h>
#include <stdint.h>

#define T_TOK 4096
#define DDIM  1024
#define HDIM  4096
#define NEXP  8
#define MAXT256 40    // 256-row tiles: sum_e ceil(cnt_e/256) <= 32 + 8
#define MAXT128 80    // derived 128-row halves

typedef short s16x8  __attribute__((ext_vector_type(8)));
typedef short s16x4  __attribute__((ext_vector_type(4)));
typedef float f32x4t __attribute__((ext_vector_type(4)));

#define GLOAD16(gp, lp) __builtin_amdgcn_global_load_lds( \
    (const __attribute__((address_space(1))) unsigned int*)(gp), \
    (__attribute__((address_space(3))) unsigned int*)(lp), 16, 0, 0)
#define SB0 __builtin_amdgcn_sched_barrier(0)

__device__ __forceinline__ unsigned short f2b(float f){
  unsigned int u = __float_as_uint(f);
  u += 0x7fffu + ((u >> 16) & 1u);   // RNE
  return (unsigned short)(u >> 16);
}

// BK=32 rows (64 B): slot ^= (row>>1)&3  (R8/R9/R12-verified involution pair)
__device__ __forceinline__ s16x8 lds_frag32(const unsigned short* base, int row, int colElem){
  int byte = row*64 + ((colElem*2) ^ (((row >> 1) & 3) << 4));
  return *(const s16x8*)((const char*)base + byte);
}
// BK=64 rows (128 B): slot ^= row&7  (R5-verified involution pair, 0 conflicts)
__device__ __forceinline__ s16x8 lds_frag64(const unsigned short* base, int row, int colElem){
  int byte = row*128 + ((colElem*2) ^ ((row & 7) << 4));
  return *(const s16x8*)((const char*)base + byte);
}

// ---------------- gate + x->bf16 conversion (fused) ----------------
__global__ void gate_kernel(const float* __restrict__ x, const float* __restrict__ Wg,
                            const float* __restrict__ bg,
                            int* __restrict__ topk_e, float* __restrict__ topk_w,
                            unsigned short* __restrict__ xb){
  const int t = blockIdx.x;
  const int lane = threadIdx.x;
  const float* xr = x + (size_t)t * DDIM;
  unsigned short* xbr = xb + (size_t)t * DDIM;
  float acc[NEXP];
  #pragma unroll
  for (int e = 0; e < NEXP; ++e) acc[e] = 0.f;
  #pragma unroll 4
  for (int it = 0; it < DDIM/64; ++it){
    int i = it*64 + lane;
    float xi = xr[i];
    xbr[i] = f2b(xi);
    const float4* wr = (const float4*)(Wg + (size_t)i * NEXP);
    float4 w0 = wr[0], w1 = wr[1];
    acc[0] += xi*w0.x; acc[1] += xi*w0.y; acc[2] += xi*w0.z; acc[3] += xi*w0.w;
    acc[4] += xi*w1.x; acc[5] += xi*w1.y; acc[6] += xi*w1.z; acc[7] += xi*w1.w;
  }
  #pragma unroll
  for (int e = 0; e < NEXP; ++e){
    float v = acc[e];
    #pragma unroll
    for (int off = 32; off > 0; off >>= 1) v += __shfl_xor(v, off, 64);
    acc[e] = v;
  }
  if (lane == 0){
    float l[NEXP], m = -1e30f;
    #pragma unroll
    for (int e = 0; e < NEXP; ++e){ l[e] = acc[e] + bg[e]; m = fmaxf(m, l[e]); }
    float p[NEXP], s = 0.f;
    #pragma unroll
    for (int e = 0; e < NEXP; ++e){ p[e] = expf(l[e] - m); s += p[e]; }
    float inv = 1.f / s;
    int a1 = 0; float v1 = -1.f;
    #pragma unroll
    for (int e = 0; e < NEXP; ++e){ p[e] *= inv; if (p[e] > v1){ v1 = p[e]; a1 = e; } }
    int a2 = -1; float v2 = -1.f;
    #pragma unroll
    for (int e = 0; e < NEXP; ++e){ if (e == a1) continue; if (p[e] > v2){ v2 = p[e]; a2 = e; } }
    topk_e[2*t]   = a1; topk_w[2*t]   = v1;
    topk_e[2*t+1] = a2; topk_w[2*t+1] = v2;
  }
}

// ---------------- routing: per-expert ordered compaction ----------------
__global__ void route_count(const int* __restrict__ topk_e, const float* __restrict__ topk_w,
                            int* __restrict__ expertList, float* __restrict__ pairW,
                            int* __restrict__ counts){
  const int e = blockIdx.x;
  const int tid = threadIdx.x;
  __shared__ int pfx[256];
  __shared__ int base_s;
  if (tid == 0) base_s = 0;
  __syncthreads();
  for (int c = 0; c < T_TOK/256; ++c){
    int t = c*256 + tid;
    int e0 = topk_e[2*t], e1 = topk_e[2*t+1];
    int sel = 0; float w = 0.f;
    if (e0 == e){ sel = 1; w = topk_w[2*t]; }
    else if (e1 == e){ sel = 1; w = topk_w[2*t+1]; }
    pfx[tid] = sel;
    __syncthreads();
    for (int off = 1; off < 256; off <<= 1){
      int v = (tid >= off) ? pfx[tid - off] : 0;
      __syncthreads();
      pfx[tid] += v;
      __syncthreads();
    }
    if (sel){
      int pos = base_s + pfx[tid] - 1;
      expertList[e*T_TOK + pos] = t;
      pairW[e*T_TOK + pos] = w;
    }
    __syncthreads();
    if (tid == 0) base_s += pfx[255];
    __syncthreads();
  }
  if (tid == 0) counts[e] = base_s;
}

// 256-row tiles
__global__ void plan_kernel(const int* __restrict__ counts, int* __restrict__ nTiles,
                            int* __restrict__ tileExpert, int* __restrict__ tileStart){
  if (blockIdx.x != 0 || threadIdx.x != 0) return;
  int nt = 0;
  for (int e = 0; e < NEXP; ++e){
    int c = counts[e];
    int tcount = (c + 255) >> 8;
    for (int i = 0; i < tcount; ++i){ tileExpert[nt] = e; tileStart[nt] = i*256; ++nt; }
  }
  *nTiles = nt;
}

// ---------------- pre-pass: W [E][K][N] fp32 -> Wt [E][N][K] bf16 ----------------
__global__ __launch_bounds__(256)
void transpose_w(const float* __restrict__ W, unsigned short* __restrict__ Wt,
                 int K, int N){
  const int e = blockIdx.z;
  const float* Wb = W + (size_t)e*K*N;
  unsigned short* Wtb = Wt + (size_t)e*K*N;
  const int n0 = blockIdx.x*64, k0 = blockIdx.y*64;
  __shared__ unsigned short t[64][72];
  const int r  = threadIdx.x >> 4;
  const int c4 = (threadIdx.x & 15) * 4;
  #pragma unroll
  for (int i = 0; i < 4; ++i){
    int k = r + i*16;
    float4 v = *(const float4*)(Wb + (size_t)(k0+k)*N + n0 + c4);
    t[c4+0][k] = f2b(v.x); t[c4+1][k] = f2b(v.y);
    t[c4+2][k] = f2b(v.z); t[c4+3][k] = f2b(v.w);
  }
  __syncthreads();
  const int kk = (threadIdx.x & 7) * 8;
  #pragma unroll
  for (int i = 0; i < 2; ++i){
    int n = (threadIdx.x >> 3) + i*32;
    s16x8 v;
    #pragma unroll
    for (int j = 0; j < 8; ++j) v[j] = (short)t[n][kk+j];
    *(s16x8*)(Wtb + (size_t)(n0+n)*K + k0 + kk) = v;
  }
}

// ======= GEMM1: 256x256, BK=64, 8 waves, 4-phase/K-tile interleave (m248 port) =======
// Phase p: {stage half-tile p of tile t+1 -> buf^1 (2 gloads)} || {frag ds_reads}
//          -> [phase 0 only: vmcnt(2)+barrier publishes tile t] -> 16-MFMA cluster -> barrier.
// Counted wait: at phase 0, outstanding = 8 (tile t, issued last K-tile) + 2 (own) -> vmcnt(2)
// retires exactly tile t's 8.  Never drains to 0 in steady state (T4).
__global__ __launch_bounds__(512, 1)
void moe_gemm8(const unsigned short* __restrict__ Abf,
               const unsigned short* __restrict__ Wt,
               const float* __restrict__ bias,
               const int* __restrict__ nTilesPtr,
               const int* __restrict__ tileExpert,
               const int* __restrict__ tileStart,
               const int* __restrict__ counts,
               const int* __restrict__ expertList,
               unsigned short* __restrict__ Hout)
{
  constexpr int ND = HDIM;
  constexpr int NB = ND / 256;
  constexpr int NT = DDIM / 64;

  const int nwg = gridDim.x;
  const int b   = blockIdx.x;
  const int q8 = nwg >> 3, r8 = nwg & 7;
  const int xcd = b & 7, ii = b >> 3;
  const int lin = (xcd < r8 ? xcd*(q8+1) : r8*(q8+1) + (xcd-r8)*q8) + ii;
  const int tile = lin / NB;
  const int n0   = (lin % NB) * 256;

  if (tile >= *nTilesPtr) return;
  const int e   = tileExpert[tile];
  const int ts  = tileStart[tile];
  const int cnt = counts[e];
  const int tid  = threadIdx.x;
  const int lane = tid & 63;
  const int wave = tid >> 6;        // 0..7
  const int wr = wave >> 2;         // 0..1 (M half)
  const int wc = wave & 3;          // 0..3 (N quarter)

  __shared__ __align__(16) unsigned short As[2][256][64];   // 64 KB
  __shared__ __align__(16) unsigned short Bs[2][256][64];   // 64 KB
  __shared__ int tokenBuf[256];

  if (tid < 256){
    int pos = ts + tid;
    int tok = 0;
    if (pos < cnt) tok = expertList[e*T_TOK + pos];
    tokenBuf[tid] = tok;
  }
  __syncthreads();

  // staging addressing: linear LDS dest; pre-swizzled global source (row&7 involution)
  const int srow = tid >> 3;                    // 0..63
  const int slot = (tid & 7) ^ (srow & 7);
  const int koff = slot * 8;
  const unsigned short* gA[4];                  // [h*2+g]: row = h*128 + g*64 + srow
  const unsigned short* gB[4];
  #pragma unroll
  for (int h = 0; h < 2; ++h)
    #pragma unroll
    for (int g = 0; g < 2; ++g){
      const int row = h*128 + g*64 + srow;
      gA[h*2+g] = Abf + (size_t)tokenBuf[row]*DDIM + koff;
      gB[h*2+g] = Wt + ((size_t)e*ND + n0 + row)*DDIM + koff;
    }

  // which: 0=A-half0, 1=A-half1, 2=B-half0, 3=B-half1 (2 gloads each)
  auto STAGE_HALF = [&](int buf, int which, int ko){
    if (which < 2){
      #pragma unroll
      for (int g = 0; g < 2; ++g)
        GLOAD16(gA[which*2+g] + ko, &As[buf][which*128 + g*64 + wave*8][0]);
    } else {
      const int h = which - 2;
      #pragma unroll
      for (int g = 0; g < 2; ++g)
        GLOAD16(gB[h*2+g] + ko, &Bs[buf][h*128 + g*64 + wave*8][0]);
    }
  };

  f32x4t acc[8][4] = {};
  const int fr = lane & 15;
  const int fq = lane >> 4;

  // prologue: stage all 4 halves of K-tile 0 into buf0
  #pragma unroll
  for (int w = 0; w < 4; ++w) STAGE_HALF(0, w, 0);

  int cur = 0;
  for (int t = 0; t < NT; ++t){
    const bool has_next = (t + 1 < NT);
    const int ko_next = (t + 1) * 64;
    const unsigned short* Ab = &As[cur][0][0];
    const unsigned short* Bb = &Bs[cur][0][0];
    s16x8 bfr[4][2];

    // ---- phase 0: publish tile t, compute quadrant 0 ----
    if (has_next){
      STAGE_HALF(cur^1, 0, ko_next);
      SB0; asm volatile("s_waitcnt vmcnt(2)" ::: "memory");
    } else {
      SB0; asm volatile("s_waitcnt vmcnt(0)" ::: "memory");
    }
    __builtin_amdgcn_s_barrier();       // tile t fills visible to all waves
    SB0;
    #pragma unroll
    for (int nf = 0; nf < 4; ++nf)
      #pragma unroll
      for (int ks = 0; ks < 2; ++ks)
        bfr[nf][ks] = lds_frag64(Bb, wc*64 + nf*16 + fr, ks*32 + fq*8);
    {
      s16x8 afr[2][2];
      #pragma unroll
      for (int i = 0; i < 2; ++i)
        #pragma unroll
        for (int ks = 0; ks < 2; ++ks)
          afr[i][ks] = lds_frag64(Ab, wr*128 + i*16 + fr, ks*32 + fq*8);
      __builtin_amdgcn_s_setprio(1);
      #pragma unroll
      for (int ks = 0; ks < 2; ++ks)
        #pragma unroll
        for (int i = 0; i < 2; ++i)
          #pragma unroll
          for (int nf = 0; nf < 4; ++nf)
            acc[i][nf] = __builtin_amdgcn_mfma_f32_16x16x32_bf16(
                afr[i][ks], bfr[nf][ks], acc[i][nf], 0, 0, 0);
      __builtin_amdgcn_s_setprio(0);
    }
    SB0;
    __builtin_amdgcn_s_barrier();
    SB0;

    // ---- phases 1..3: stage half q of t+1, compute quadrant q ----
    #pragma unroll
    for (int q = 1; q < 4; ++q){
      if (has_next) STAGE_HALF(cur^1, q, ko_next);
      s16x8 afr[2][2];
      #pragma unroll
      for (int i = 0; i < 2; ++i)
        #pragma unroll
        for (int ks = 0; ks < 2; ++ks)
          afr[i][ks] = lds_frag64(Ab, wr*128 + q*32 + i*16 + fr, ks*32 + fq*8);
      __builtin_amdgcn_s_setprio(1);
      #pragma unroll
      for (int ks = 0; ks < 2; ++ks)
        #pragma unroll
        for (int i = 0; i < 2; ++i)
          #pragma unroll
          for (int nf = 0; nf < 4; ++nf)
            acc[q*2+i][nf] = __builtin_amdgcn_mfma_f32_16x16x32_bf16(
                afr[i][ks], bfr[nf][ks], acc[q*2+i][nf], 0, 0, 0);
      __builtin_amdgcn_s_setprio(0);
      SB0;
      __builtin_amdgcn_s_barrier();
      SB0;
    }
    cur ^= 1;
  }

  // ---- epilogue: relu(acc + b1) -> Hout (bf16), 256-row tile ----
  const int rbase = wr*128 + fq*4;
  const int cbase = wc*64 + fr;
  #pragma unroll
  for (int mf = 0; mf < 8; ++mf){
    #pragma unroll
    for (int nf = 0; nf < 4; ++nf){
      int c = cbase + nf*16;
      float bsv = bias[e*HDIM + n0 + c];
      #pragma unroll
      for (int j = 0; j < 4; ++j){
        int rr = rbase + mf*16 + j;
        float v = fmaxf(acc[mf][nf][j] + bsv, 0.f);
        __builtin_nontemporal_store((unsigned short)f2b(v),
            &Hout[(size_t)(tile*256 + rr)*HDIM + n0 + c]);
      }
    }
  }
}

// ======= GEMM2: R12 kernel (128x128, BK=32, 4 waves, dbuf, counted vmcnt) =======
// Reads 128-row halves of the 256-row plan: t128 -> (tile256 = t128>>1, half = t128&1).
template<int KS>
__global__ __launch_bounds__(256, 4)
void moe_gemm2(const unsigned short* __restrict__ Abf,   // Hact [tile256*256+r][HDIM]
               const unsigned short* __restrict__ Wt,    // W2t bf16 [E][DDIM][HDIM]
               const float* __restrict__ bias,
               const int* __restrict__ nTilesPtr,
               const int* __restrict__ tileExpert,
               const int* __restrict__ tileStart,
               const int* __restrict__ counts,
               const int* __restrict__ expertList,
               const float* __restrict__ pairW,
               float* __restrict__ out)
{
  constexpr int KD = HDIM;
  constexpr int ND = DDIM;
  constexpr int NB = ND / 128;
  constexpr int NTfull = KD / 32;

  const int nwg = gridDim.x;
  const int b   = blockIdx.x;
  const int q8 = nwg >> 3, r8 = nwg & 7;
  const int xcd = b & 7, ii = b >> 3;
  const int lin = (xcd < r8 ? xcd*(q8+1) : r8*(q8+1) + (xcd-r8)*q8) + ii;
  const int t128 = lin / NB;
  const int n0   = (lin % NB) * 128;
  const int kz   = blockIdx.y;

  if ((t128 >> 1) >= *nTilesPtr) return;
  const int e   = tileExpert[t128 >> 1];
  const int ts  = tileStart[t128 >> 1] + (t128 & 1) * 128;
  const int cnt = counts[e];
  const int tid  = threadIdx.x;
  const int lane = tid & 63;
  const int wave = tid >> 6;
  const int wm = (wave >> 1) * 64;
  const int wn = (wave & 1) * 64;

  __shared__ __align__(16) unsigned short As[2][128][32];
  __shared__ __align__(16) unsigned short Bs[2][128][32];
  __shared__ int   tokenBuf[128];
  __shared__ float wBuf[128];

  if (tid < 128){
    int pos = ts + tid;
    int tok = 0; float w = 0.f;
    if (pos < cnt){ tok = expertList[e*T_TOK + pos]; w = pairW[e*T_TOK + pos]; }
    tokenBuf[tid] = tok; wBuf[tid] = w;
  }
  __syncthreads();

  const int srow = tid >> 2;                                  // 0..63
  const int slot = (tid & 3) ^ ((tid >> 3) & 3);
  const int koff = slot * 8;
  const unsigned short* gA[2];
  const unsigned short* gB[2];
  #pragma unroll
  for (int g = 0; g < 2; ++g){
    const int row = g*64 + srow;
    gA[g] = Abf + (size_t)(t128*128 + row)*HDIM + koff;
    gB[g] = Wt + ((size_t)e*ND + n0 + row)*KD + koff;
  }

  auto STAGE = [&](int buf, int ko){
    unsigned short* la = &As[buf][wave*16][0];
    unsigned short* lb = &Bs[buf][wave*16][0];
    #pragma unroll
    for (int g = 0; g < 2; ++g){
      GLOAD16(gA[g] + ko, la + g*2048);
      GLOAD16(gB[g] + ko, lb + g*2048);
    }
  };

  f32x4t acc[4][4] = {};
  const int fr = lane & 15;
  const int fq = lane >> 4;

  const int kt0 = (kz * NTfull) / KS;
  const int kt1 = ((kz + 1) * NTfull) / KS;
  const int NTl = kt1 - kt0;

  STAGE(0, kt0*32);

  int cur = 0;
  for (int t = 0; t < NTl; ++t){
    if (t + 1 < NTl){
      STAGE(cur ^ 1, (kt0 + t + 1)*32);
      SB0; asm volatile("s_waitcnt vmcnt(4)" ::: "memory");
    } else {
      SB0; asm volatile("s_waitcnt vmcnt(0)" ::: "memory");
    }
    __builtin_amdgcn_s_barrier();
    SB0;

    const unsigned short* Ab = &As[cur][0][0];
    const unsigned short* Bb = &Bs[cur][0][0];
    s16x8 bfr[4], afr[4];
    #pragma unroll
    for (int nf = 0; nf < 4; ++nf) bfr[nf] = lds_frag32(Bb, wn + nf*16 + fr, fq*8);
    #pragma unroll
    for (int mf = 0; mf < 4; ++mf) afr[mf] = lds_frag32(Ab, wm + mf*16 + fr, fq*8);
    #pragma unroll
    for (int mf = 0; mf < 4; ++mf)
      #pragma unroll
      for (int nf = 0; nf < 4; ++nf)
        acc[mf][nf] = __builtin_amdgcn_mfma_f32_16x16x32_bf16(afr[mf], bfr[nf], acc[mf][nf], 0, 0, 0);

    SB0;
    __builtin_amdgcn_s_barrier();
    SB0;
    cur ^= 1;
  }

  const int rbase = wm + fq*4;
  const int cbase = wn + fr;
  #pragma unroll
  for (int mf = 0; mf < 4; ++mf){
    #pragma unroll
    for (int j = 0; j < 4; ++j){
      int rr = rbase + mf*16 + j;
      if (ts + rr < cnt){
        int tok = tokenBuf[rr];
        float w = wBuf[rr];
        #pragma unroll
        for (int nf = 0; nf < 4; ++nf){
          int c = cbase + nf*16;
          float v = acc[mf][nf][j];
          if (kz == 0) v += bias[e*DDIM + n0 + c];
          atomicAdd(out + (size_t)tok*DDIM + n0 + c, w * v);
        }
      }
    }
  }
}

extern "C" void kernel_launch(void* const* d_in, const int* in_sizes, int n_in,
                              void* d_out, int out_size, void* d_ws, size_t ws_size,
                              hipStream_t stream){
  const float* x  = (const float*)d_in[0];
  const float* Wg = (const float*)d_in[1];
  const float* bg = (const float*)d_in[2];
  const float* W1 = (const float*)d_in[3];
  const float* b1 = (const float*)d_in[4];
  const float* W2 = (const float*)d_in[5];
  const float* b2 = (const float*)d_in[6];
  float* out = (float*)d_out;

  char* p = (char*)d_ws;
  int*   topk_e     = (int*)p;   p += (size_t)T_TOK*2*sizeof(int);
  float* topk_w     = (float*)p; p += (size_t)T_TOK*2*sizeof(float);
  int*   counts     = (int*)p;   p += 8*sizeof(int);
  int*   nTiles     = (int*)p;   p += 8*sizeof(int);
  int*   tileExpert = (int*)p;   p += 128*sizeof(int);
  int*   tileStart  = (int*)p;   p += 128*sizeof(int);
  int*   expertList = (int*)p;   p += (size_t)NEXP*T_TOK*sizeof(int);
  float* pairW      = (float*)p; p += (size_t)NEXP*T_TOK*sizeof(float);
  p = (char*)(((uintptr_t)p + 255) & ~(uintptr_t)255);
  unsigned short* xb = (unsigned short*)p;    // 8 MB
  p += (size_t)T_TOK*DDIM*sizeof(unsigned short);
  p = (char*)(((uintptr_t)p + 255) & ~(uintptr_t)255);
  unsigned short* Wtbuf = (unsigned short*)p; // 67 MB (W1t, then W2t)
  p += (size_t)NEXP*DDIM*HDIM*sizeof(unsigned short);
  p = (char*)(((uintptr_t)p + 255) & ~(uintptr_t)255);
  unsigned short* Hact = (unsigned short*)p;  // 40*256*4096*2 = 84 MB

  hipMemsetAsync(d_out, 0, (size_t)T_TOK*DDIM*sizeof(float), stream);
  gate_kernel<<<T_TOK, 64, 0, stream>>>(x, Wg, bg, topk_e, topk_w, xb);
  route_count<<<NEXP, 256, 0, stream>>>(topk_e, topk_w, expertList, pairW, counts);
  plan_kernel<<<1, 1, 0, stream>>>(counts, nTiles, tileExpert, tileStart);

  // W1 [D][H] -> W1t [H][D]
  transpose_w<<<dim3(HDIM/64, DDIM/64, NEXP), 256, 0, stream>>>(W1, Wtbuf, DDIM, HDIM);
  moe_gemm8<<<MAXT256*(HDIM/256), 512, 0, stream>>>(
      xb, Wtbuf, b1, nTiles, tileExpert, tileStart, counts, expertList, Hact);

  // W2 [H][D] -> W2t [D][H]
  transpose_w<<<dim3(DDIM/64, HDIM/64, NEXP), 256, 0, stream>>>(W2, Wtbuf, HDIM, DDIM);
  moe_gemm2<2><<<dim3(MAXT128*(DDIM/128), 2), 256, 0, stream>>>(
      Hact, Wtbuf, b2, nTiles, tileExpert, tileStart, counts, expertList, pairW, out);
}

// Round 17
// 384.335 us; speedup vs baseline: 1.1376x; 1.0576x over previous
//
#include <hip/hip_runtime.h>
#include <stdint.h>

#define T_TOK 4096
#define DDIM  1024
#define HDIM  4096
#define NEXP  8
#define MAXTILES 72   // ceil(8192/128) + 8 experts of padding

typedef short s16x8  __attribute__((ext_vector_type(8)));
typedef float f32x4t __attribute__((ext_vector_type(4)));

#define GLOAD16(gp, lp) __builtin_amdgcn_global_load_lds( \
    (const __attribute__((address_space(1))) unsigned int*)(gp), \
    (__attribute__((address_space(3))) unsigned int*)(lp), 16, 0, 0)
#define SB0 __builtin_amdgcn_sched_barrier(0)

__device__ __forceinline__ unsigned short f2b(float f){
  unsigned int u = __float_as_uint(f);
  u += 0x7fffu + ((u >> 16) & 1u);   // RNE
  return (unsigned short)(u >> 16);
}

// BK=32 rows are 64 B (4 x 16B slots). Swizzle: slot ^= (row>>1)&3 (R8/R9/R12-verified pair).
__device__ __forceinline__ s16x8 lds_frag(const unsigned short* base, int row, int colElem){
  int byte = row*64 + ((colElem*2) ^ (((row >> 1) & 3) << 4));
  return *(const s16x8*)((const char*)base + byte);
}

// ---------------- gate + x->bf16 conversion (fused) ----------------
__global__ void gate_kernel(const float* __restrict__ x, const float* __restrict__ Wg,
                            const float* __restrict__ bg,
                            int* __restrict__ topk_e, float* __restrict__ topk_w,
                            unsigned short* __restrict__ xb){
  const int t = blockIdx.x;
  const int lane = threadIdx.x;
  const float* xr = x + (size_t)t * DDIM;
  unsigned short* xbr = xb + (size_t)t * DDIM;
  float acc[NEXP];
  #pragma unroll
  for (int e = 0; e < NEXP; ++e) acc[e] = 0.f;
  #pragma unroll 4
  for (int it = 0; it < DDIM/64; ++it){
    int i = it*64 + lane;
    float xi = xr[i];
    xbr[i] = f2b(xi);                      // fused conv_x
    const float4* wr = (const float4*)(Wg + (size_t)i * NEXP);
    float4 w0 = wr[0], w1 = wr[1];
    acc[0] += xi*w0.x; acc[1] += xi*w0.y; acc[2] += xi*w0.z; acc[3] += xi*w0.w;
    acc[4] += xi*w1.x; acc[5] += xi*w1.y; acc[6] += xi*w1.z; acc[7] += xi*w1.w;
  }
  #pragma unroll
  for (int e = 0; e < NEXP; ++e){
    float v = acc[e];
    #pragma unroll
    for (int off = 32; off > 0; off >>= 1) v += __shfl_xor(v, off, 64);
    acc[e] = v;
  }
  if (lane == 0){
    float l[NEXP], m = -1e30f;
    #pragma unroll
    for (int e = 0; e < NEXP; ++e){ l[e] = acc[e] + bg[e]; m = fmaxf(m, l[e]); }
    float p[NEXP], s = 0.f;
    #pragma unroll
    for (int e = 0; e < NEXP; ++e){ p[e] = expf(l[e] - m); s += p[e]; }
    float inv = 1.f / s;
    int a1 = 0; float v1 = -1.f;
    #pragma unroll
    for (int e = 0; e < NEXP; ++e){ p[e] *= inv; if (p[e] > v1){ v1 = p[e]; a1 = e; } }
    int a2 = -1; float v2 = -1.f;
    #pragma unroll
    for (int e = 0; e < NEXP; ++e){ if (e == a1) continue; if (p[e] > v2){ v2 = p[e]; a2 = e; } }
    topk_e[2*t]   = a1; topk_w[2*t]   = v1;
    topk_e[2*t+1] = a2; topk_w[2*t+1] = v2;
  }
}

// ---------------- routing: per-expert ordered compaction ----------------
__global__ void route_count(const int* __restrict__ topk_e, const float* __restrict__ topk_w,
                            int* __restrict__ expertList, float* __restrict__ pairW,
                            int* __restrict__ counts){
  const int e = blockIdx.x;
  const int tid = threadIdx.x;
  __shared__ int pfx[256];
  __shared__ int base_s;
  if (tid == 0) base_s = 0;
  __syncthreads();
  for (int c = 0; c < T_TOK/256; ++c){
    int t = c*256 + tid;
    int e0 = topk_e[2*t], e1 = topk_e[2*t+1];
    int sel = 0; float w = 0.f;
    if (e0 == e){ sel = 1; w = topk_w[2*t]; }
    else if (e1 == e){ sel = 1; w = topk_w[2*t+1]; }
    pfx[tid] = sel;
    __syncthreads();
    for (int off = 1; off < 256; off <<= 1){
      int v = (tid >= off) ? pfx[tid - off] : 0;
      __syncthreads();
      pfx[tid] += v;
      __syncthreads();
    }
    if (sel){
      int pos = base_s + pfx[tid] - 1;
      expertList[e*T_TOK + pos] = t;
      pairW[e*T_TOK + pos] = w;
    }
    __syncthreads();
    if (tid == 0) base_s += pfx[255];
    __syncthreads();
  }
  if (tid == 0) counts[e] = base_s;
}

__global__ void plan_kernel(const int* __restrict__ counts, int* __restrict__ nTiles,
                            int* __restrict__ tileExpert, int* __restrict__ tileStart){
  if (blockIdx.x != 0 || threadIdx.x != 0) return;
  int nt = 0;
  for (int e = 0; e < NEXP; ++e){
    int c = counts[e];
    int tcount = (c + 127) >> 7;
    for (int i = 0; i < tcount; ++i){ tileExpert[nt] = e; tileStart[nt] = i*128; ++nt; }
  }
  *nTiles = nt;
}

// ---------------- pre-pass: W [E][K][N] fp32 -> Wt [E][N][K] bf16 ----------------
__global__ __launch_bounds__(256)
void transpose_w(const float* __restrict__ W, unsigned short* __restrict__ Wt,
                 int K, int N){
  const int e = blockIdx.z;
  const float* Wb = W + (size_t)e*K*N;
  unsigned short* Wtb = Wt + (size_t)e*K*N;
  const int n0 = blockIdx.x*64, k0 = blockIdx.y*64;
  __shared__ unsigned short t[64][72];
  const int r  = threadIdx.x >> 4;
  const int c4 = (threadIdx.x & 15) * 4;
  #pragma unroll
  for (int i = 0; i < 4; ++i){
    int k = r + i*16;
    float4 v = *(const float4*)(Wb + (size_t)(k0+k)*N + n0 + c4);
    t[c4+0][k] = f2b(v.x); t[c4+1][k] = f2b(v.y);
    t[c4+2][k] = f2b(v.z); t[c4+3][k] = f2b(v.w);
  }
  __syncthreads();
  const int kk = (threadIdx.x & 7) * 8;
  #pragma unroll
  for (int i = 0; i < 2; ++i){
    int n = (threadIdx.x >> 3) + i*32;
    s16x8 v;
    #pragma unroll
    for (int j = 0; j < 8; ++j) v[j] = (short)t[n][kk+j];
    *(s16x8*)(Wtb + (size_t)(n0+n)*K + k0 + kk) = v;
  }
}

// ------- grouped GEMM (R12, session best): 128x128, BK=32, 4 waves, dbuf,
// 4 blocks/CU, top-placed counted vmcnt(4), T2 involution swizzle,
// n0-fastest decode (A panel L2-shared per XCD) + bijective XCD swizzle. -------
template<int LAYER, int KS>
__global__ __launch_bounds__(256, 4)
void moe_gemm(const unsigned short* __restrict__ Abf,
              const unsigned short* __restrict__ Wt,
              const float* __restrict__ bias,
              const int* __restrict__ nTilesPtr,
              const int* __restrict__ tileExpert,
              const int* __restrict__ tileStart,
              const int* __restrict__ counts,
              const int* __restrict__ expertList,
              const float* __restrict__ pairW,
              unsigned short* __restrict__ Hout,
              float* __restrict__ out)
{
  constexpr int KD = (LAYER == 1) ? DDIM : HDIM;
  constexpr int ND = (LAYER == 1) ? HDIM : DDIM;
  constexpr int NB = ND / 128;
  constexpr int NTfull = KD / 32;

  const int nwg = gridDim.x;
  const int b   = blockIdx.x;
  const int q8 = nwg >> 3, r8 = nwg & 7;
  const int xcd = b & 7, ii = b >> 3;
  const int lin = (xcd < r8 ? xcd*(q8+1) : r8*(q8+1) + (xcd-r8)*q8) + ii;
  const int tile = lin / NB;
  const int n0   = (lin % NB) * 128;
  const int kz   = blockIdx.y;

  if (tile >= *nTilesPtr) return;
  const int e   = tileExpert[tile];
  const int ts  = tileStart[tile];
  const int cnt = counts[e];
  const int tid  = threadIdx.x;
  const int lane = tid & 63;
  const int wave = tid >> 6;
  const int wm = (wave >> 1) * 64;
  const int wn = (wave & 1) * 64;

  __shared__ __align__(16) unsigned short As[2][128][32];   // 16 KB
  __shared__ __align__(16) unsigned short Bs[2][128][32];   // 16 KB
  __shared__ int   tokenBuf[128];
  __shared__ float wBuf[128];

  if (tid < 128){
    int pos = ts + tid;
    int tok = 0; float w = 0.f;
    if (pos < cnt){ tok = expertList[e*T_TOK + pos]; w = pairW[e*T_TOK + pos]; }
    tokenBuf[tid] = tok; wBuf[tid] = w;
  }
  __syncthreads();

  const int srow = tid >> 2;                                  // 0..63
  const int slot = (tid & 3) ^ ((tid >> 3) & 3);              // (row>>1)&3 == (tid>>3)&3
  const int koff = slot * 8;
  const unsigned short* gA[2];
  const unsigned short* gB[2];
  #pragma unroll
  for (int g = 0; g < 2; ++g){
    const int row = g*64 + srow;
    if (LAYER == 1) gA[g] = Abf + (size_t)tokenBuf[row]*DDIM + koff;
    else            gA[g] = Abf + (size_t)(tile*128 + row)*HDIM + koff;
    gB[g] = Wt + ((size_t)e*ND + n0 + row)*KD + koff;
  }

  auto STAGE = [&](int buf, int ko){
    unsigned short* la = &As[buf][wave*16][0];   // wave-uniform base + lane*16B
    unsigned short* lb = &Bs[buf][wave*16][0];
    #pragma unroll
    for (int g = 0; g < 2; ++g){
      GLOAD16(gA[g] + ko, la + g*2048);
      GLOAD16(gB[g] + ko, lb + g*2048);
    }
  };

  f32x4t acc[4][4] = {};
  const int fr = lane & 15;
  const int fq = lane >> 4;

  const int kt0 = (kz * NTfull) / KS;
  const int kt1 = ((kz + 1) * NTfull) / KS;
  const int NTl = kt1 - kt0;

  STAGE(0, kt0*32);

  int cur = 0;
  for (int t = 0; t < NTl; ++t){
    if (t + 1 < NTl){
      STAGE(cur ^ 1, (kt0 + t + 1)*32);
      SB0; asm volatile("s_waitcnt vmcnt(4)" ::: "memory");
    } else {
      SB0; asm volatile("s_waitcnt vmcnt(0)" ::: "memory");
    }
    __builtin_amdgcn_s_barrier();       // all waves' cur fills visible
    SB0;

    const unsigned short* Ab = &As[cur][0][0];
    const unsigned short* Bb = &Bs[cur][0][0];
    s16x8 bfr[4], afr[4];
    #pragma unroll
    for (int nf = 0; nf < 4; ++nf) bfr[nf] = lds_frag(Bb, wn + nf*16 + fr, fq*8);
    #pragma unroll
    for (int mf = 0; mf < 4; ++mf) afr[mf] = lds_frag(Ab, wm + mf*16 + fr, fq*8);
    #pragma unroll
    for (int mf = 0; mf < 4; ++mf)
      #pragma unroll
      for (int nf = 0; nf < 4; ++nf)
        acc[mf][nf] = __builtin_amdgcn_mfma_f32_16x16x32_bf16(afr[mf], bfr[nf], acc[mf][nf], 0, 0, 0);

    SB0;
    __builtin_amdgcn_s_barrier();       // readers done -> buf cur overwritable next iter
    SB0;
    cur ^= 1;
  }

  const int rbase = wm + fq*4;
  const int cbase = wn + fr;
  if (LAYER == 1){
    #pragma unroll
    for (int mf = 0; mf < 4; ++mf){
      #pragma unroll
      for (int nf = 0; nf < 4; ++nf){
        int c = cbase + nf*16;
        float bsv = bias[e*HDIM + n0 + c];
        #pragma unroll
        for (int j = 0; j < 4; ++j){
          int rr = rbase + mf*16 + j;
          float v = fmaxf(acc[mf][nf][j] + bsv, 0.f);
          __builtin_nontemporal_store((unsigned short)f2b(v),
              &Hout[(size_t)(tile*128 + rr)*HDIM + n0 + c]);
        }
      }
    }
  } else {
    #pragma unroll
    for (int mf = 0; mf < 4; ++mf){
      #pragma unroll
      for (int j = 0; j < 4; ++j){
        int rr = rbase + mf*16 + j;
        if (ts + rr < cnt){
          int tok = tokenBuf[rr];
          float w = wBuf[rr];
          #pragma unroll
          for (int nf = 0; nf < 4; ++nf){
            int c = cbase + nf*16;
            float v = acc[mf][nf][j];
            if (kz == 0) v += bias[e*DDIM + n0 + c];
            atomicAdd(out + (size_t)tok*DDIM + n0 + c, w * v);
          }
        }
      }
    }
  }
}

extern "C" void kernel_launch(void* const* d_in, const int* in_sizes, int n_in,
                              void* d_out, int out_size, void* d_ws, size_t ws_size,
                              hipStream_t stream){
  const float* x  = (const float*)d_in[0];
  const float* Wg = (const float*)d_in[1];
  const float* bg = (const float*)d_in[2];
  const float* W1 = (const float*)d_in[3];
  const float* b1 = (const float*)d_in[4];
  const float* W2 = (const float*)d_in[5];
  const float* b2 = (const float*)d_in[6];
  float* out = (float*)d_out;

  char* p = (char*)d_ws;
  int*   topk_e     = (int*)p;   p += (size_t)T_TOK*2*sizeof(int);
  float* topk_w     = (float*)p; p += (size_t)T_TOK*2*sizeof(float);
  int*   counts     = (int*)p;   p += 8*sizeof(int);
  int*   nTiles     = (int*)p;   p += 8*sizeof(int);
  int*   tileExpert = (int*)p;   p += 128*sizeof(int);
  int*   tileStart  = (int*)p;   p += 128*sizeof(int);
  int*   expertList = (int*)p;   p += (size_t)NEXP*T_TOK*sizeof(int);
  float* pairW      = (float*)p; p += (size_t)NEXP*T_TOK*sizeof(float);
  p = (char*)(((uintptr_t)p + 255) & ~(uintptr_t)255);
  unsigned short* xb = (unsigned short*)p;    // 8 MB
  p += (size_t)T_TOK*DDIM*sizeof(unsigned short);
  p = (char*)(((uintptr_t)p + 255) & ~(uintptr_t)255);
  unsigned short* Wtbuf = (unsigned short*)p; // 67 MB (W1t, then W2t)
  p += (size_t)NEXP*DDIM*HDIM*sizeof(unsigned short);
  p = (char*)(((uintptr_t)p + 255) & ~(uintptr_t)255);
  unsigned short* Hact = (unsigned short*)p;  // 75.5 MB

  hipMemsetAsync(d_out, 0, (size_t)T_TOK*DDIM*sizeof(float), stream);
  gate_kernel<<<T_TOK, 64, 0, stream>>>(x, Wg, bg, topk_e, topk_w, xb);
  route_count<<<NEXP, 256, 0, stream>>>(topk_e, topk_w, expertList, pairW, counts);
  plan_kernel<<<1, 1, 0, stream>>>(counts, nTiles, tileExpert, tileStart);

  transpose_w<<<dim3(HDIM/64, DDIM/64, NEXP), 256, 0, stream>>>(W1, Wtbuf, DDIM, HDIM);
  moe_gemm<1,1><<<dim3(MAXTILES*(HDIM/128), 1), 256, 0, stream>>>(
      xb, Wtbuf, b1, nTiles, tileExpert, tileStart, counts, expertList, pairW, Hact, nullptr);

  transpose_w<<<dim3(DDIM/64, HDIM/64, NEXP), 256, 0, stream>>>(W2, Wtbuf, HDIM, DDIM);
  moe_gemm<2,2><<<dim3(MAXTILES*(DDIM/128), 2), 256, 0, stream>>>(
      Hact, Wtbuf, b2, nTiles, tileExpert, tileStart, counts, expertList, pairW, nullptr, out);
}

// Round 18
// 384.230 us; speedup vs baseline: 1.1379x; 1.0003x over previous
//
#include <hip/hip_runtime.h>
#include <stdint.h>

#define T_TOK 4096
#define DDIM  1024
#define HDIM  4096
#define NEXP  8
#define MAXTILES 72   // ceil(8192/128) + 8 experts of padding

typedef short s16x8  __attribute__((ext_vector_type(8)));
typedef float f32x4t __attribute__((ext_vector_type(4)));

#define GLOAD16(gp, lp) __builtin_amdgcn_global_load_lds( \
    (const __attribute__((address_space(1))) unsigned int*)(gp), \
    (__attribute__((address_space(3))) unsigned int*)(lp), 16, 0, 0)
#define SB0 __builtin_amdgcn_sched_barrier(0)

__device__ __forceinline__ unsigned short f2b(float f){
  unsigned int u = __float_as_uint(f);
  u += 0x7fffu + ((u >> 16) & 1u);   // RNE
  return (unsigned short)(u >> 16);
}

// BK=32 rows are 64 B (4 x 16B slots). Swizzle: slot ^= (row>>1)&3 (verified involution pair).
__device__ __forceinline__ s16x8 lds_frag(const unsigned short* base, int row, int colElem){
  int byte = row*64 + ((colElem*2) ^ (((row >> 1) & 3) << 4));
  return *(const s16x8*)((const char*)base + byte);
}

// ---------------- gate + x->bf16 conversion (fused) ----------------
__global__ void gate_kernel(const float* __restrict__ x, const float* __restrict__ Wg,
                            const float* __restrict__ bg,
                            int* __restrict__ topk_e, float* __restrict__ topk_w,
                            unsigned short* __restrict__ xb){
  const int t = blockIdx.x;
  const int lane = threadIdx.x;
  const float* xr = x + (size_t)t * DDIM;
  unsigned short* xbr = xb + (size_t)t * DDIM;
  float acc[NEXP];
  #pragma unroll
  for (int e = 0; e < NEXP; ++e) acc[e] = 0.f;
  #pragma unroll 4
  for (int it = 0; it < DDIM/64; ++it){
    int i = it*64 + lane;
    float xi = xr[i];
    xbr[i] = f2b(xi);                      // fused conv_x
    const float4* wr = (const float4*)(Wg + (size_t)i * NEXP);
    float4 w0 = wr[0], w1 = wr[1];
    acc[0] += xi*w0.x; acc[1] += xi*w0.y; acc[2] += xi*w0.z; acc[3] += xi*w0.w;
    acc[4] += xi*w1.x; acc[5] += xi*w1.y; acc[6] += xi*w1.z; acc[7] += xi*w1.w;
  }
  #pragma unroll
  for (int e = 0; e < NEXP; ++e){
    float v = acc[e];
    #pragma unroll
    for (int off = 32; off > 0; off >>= 1) v += __shfl_xor(v, off, 64);
    acc[e] = v;
  }
  if (lane == 0){
    float l[NEXP], m = -1e30f;
    #pragma unroll
    for (int e = 0; e < NEXP; ++e){ l[e] = acc[e] + bg[e]; m = fmaxf(m, l[e]); }
    float p[NEXP], s = 0.f;
    #pragma unroll
    for (int e = 0; e < NEXP; ++e){ p[e] = expf(l[e] - m); s += p[e]; }
    float inv = 1.f / s;
    int a1 = 0; float v1 = -1.f;
    #pragma unroll
    for (int e = 0; e < NEXP; ++e){ p[e] *= inv; if (p[e] > v1){ v1 = p[e]; a1 = e; } }
    int a2 = -1; float v2 = -1.f;
    #pragma unroll
    for (int e = 0; e < NEXP; ++e){ if (e == a1) continue; if (p[e] > v2){ v2 = p[e]; a2 = e; } }
    topk_e[2*t]   = a1; topk_w[2*t]   = v1;
    topk_e[2*t+1] = a2; topk_w[2*t+1] = v2;
  }
}

// ---------------- routing: per-expert ordered compaction ----------------
__global__ void route_count(const int* __restrict__ topk_e, const float* __restrict__ topk_w,
                            int* __restrict__ expertList, float* __restrict__ pairW,
                            int* __restrict__ counts){
  const int e = blockIdx.x;
  const int tid = threadIdx.x;
  __shared__ int pfx[256];
  __shared__ int base_s;
  if (tid == 0) base_s = 0;
  __syncthreads();
  for (int c = 0; c < T_TOK/256; ++c){
    int t = c*256 + tid;
    int e0 = topk_e[2*t], e1 = topk_e[2*t+1];
    int sel = 0; float w = 0.f;
    if (e0 == e){ sel = 1; w = topk_w[2*t]; }
    else if (e1 == e){ sel = 1; w = topk_w[2*t+1]; }
    pfx[tid] = sel;
    __syncthreads();
    for (int off = 1; off < 256; off <<= 1){
      int v = (tid >= off) ? pfx[tid - off] : 0;
      __syncthreads();
      pfx[tid] += v;
      __syncthreads();
    }
    if (sel){
      int pos = base_s + pfx[tid] - 1;
      expertList[e*T_TOK + pos] = t;
      pairW[e*T_TOK + pos] = w;
    }
    __syncthreads();
    if (tid == 0) base_s += pfx[255];
    __syncthreads();
  }
  if (tid == 0) counts[e] = base_s;
}

__global__ void plan_kernel(const int* __restrict__ counts, int* __restrict__ nTiles,
                            int* __restrict__ tileExpert, int* __restrict__ tileStart){
  if (blockIdx.x != 0 || threadIdx.x != 0) return;
  int nt = 0;
  for (int e = 0; e < NEXP; ++e){
    int c = counts[e];
    int tcount = (c + 127) >> 7;
    for (int i = 0; i < tcount; ++i){ tileExpert[nt] = e; tileStart[nt] = i*128; ++nt; }
  }
  *nTiles = nt;
}

// ---------------- pre-pass: W [E][K][N] fp32 -> Wt [E][N][K] bf16 ----------------
__global__ __launch_bounds__(256)
void transpose_w(const float* __restrict__ W, unsigned short* __restrict__ Wt,
                 int K, int N){
  const int e = blockIdx.z;
  const float* Wb = W + (size_t)e*K*N;
  unsigned short* Wtb = Wt + (size_t)e*K*N;
  const int n0 = blockIdx.x*64, k0 = blockIdx.y*64;
  __shared__ unsigned short t[64][72];
  const int r  = threadIdx.x >> 4;
  const int c4 = (threadIdx.x & 15) * 4;
  #pragma unroll
  for (int i = 0; i < 4; ++i){
    int k = r + i*16;
    float4 v = *(const float4*)(Wb + (size_t)(k0+k)*N + n0 + c4);
    t[c4+0][k] = f2b(v.x); t[c4+1][k] = f2b(v.y);
    t[c4+2][k] = f2b(v.z); t[c4+3][k] = f2b(v.w);
  }
  __syncthreads();
  const int kk = (threadIdx.x & 7) * 8;
  #pragma unroll
  for (int i = 0; i < 2; ++i){
    int n = (threadIdx.x >> 3) + i*32;
    s16x8 v;
    #pragma unroll
    for (int j = 0; j < 8; ++j) v[j] = (short)t[n][kk+j];
    *(s16x8*)(Wtb + (size_t)(n0+n)*K + k0 + kk) = v;
  }
}

// ------- grouped GEMM (session best): 128x128, BK=32, 4 waves, dbuf,
// 4 blocks/CU, top-placed counted vmcnt(4), T2 involution swizzle,
// n0-fastest decode (A panel L2-shared per XCD) + bijective XCD swizzle. -------
template<int LAYER, int KS>
__global__ __launch_bounds__(256, 4)
void moe_gemm(const unsigned short* __restrict__ Abf,
              const unsigned short* __restrict__ Wt,
              const float* __restrict__ bias,
              const int* __restrict__ nTilesPtr,
              const int* __restrict__ tileExpert,
              const int* __restrict__ tileStart,
              const int* __restrict__ counts,
              const int* __restrict__ expertList,
              const float* __restrict__ pairW,
              unsigned short* __restrict__ Hout,
              float* __restrict__ out)
{
  constexpr int KD = (LAYER == 1) ? DDIM : HDIM;
  constexpr int ND = (LAYER == 1) ? HDIM : DDIM;
  constexpr int NB = ND / 128;
  constexpr int NTfull = KD / 32;

  const int nwg = gridDim.x;
  const int b   = blockIdx.x;
  const int q8 = nwg >> 3, r8 = nwg & 7;
  const int xcd = b & 7, ii = b >> 3;
  const int lin = (xcd < r8 ? xcd*(q8+1) : r8*(q8+1) + (xcd-r8)*q8) + ii;
  const int tile = lin / NB;
  const int n0   = (lin % NB) * 128;
  const int kz   = blockIdx.y;

  if (tile >= *nTilesPtr) return;
  const int e   = tileExpert[tile];
  const int ts  = tileStart[tile];
  const int cnt = counts[e];
  const int tid  = threadIdx.x;
  const int lane = tid & 63;
  const int wave = tid >> 6;
  const int wm = (wave >> 1) * 64;
  const int wn = (wave & 1) * 64;

  __shared__ __align__(16) unsigned short As[2][128][32];   // 16 KB
  __shared__ __align__(16) unsigned short Bs[2][128][32];   // 16 KB
  __shared__ int   tokenBuf[128];
  __shared__ float wBuf[128];

  if (tid < 128){
    int pos = ts + tid;
    int tok = 0; float w = 0.f;
    if (pos < cnt){ tok = expertList[e*T_TOK + pos]; w = pairW[e*T_TOK + pos]; }
    tokenBuf[tid] = tok; wBuf[tid] = w;
  }
  __syncthreads();

  const int srow = tid >> 2;                                  // 0..63
  const int slot = (tid & 3) ^ ((tid >> 3) & 3);              // (row>>1)&3 == (tid>>3)&3
  const int koff = slot * 8;
  const unsigned short* gA[2];
  const unsigned short* gB[2];
  #pragma unroll
  for (int g = 0; g < 2; ++g){
    const int row = g*64 + srow;
    if (LAYER == 1) gA[g] = Abf + (size_t)tokenBuf[row]*DDIM + koff;
    else            gA[g] = Abf + (size_t)(tile*128 + row)*HDIM + koff;
    gB[g] = Wt + ((size_t)e*ND + n0 + row)*KD + koff;
  }

  auto STAGE = [&](int buf, int ko){
    unsigned short* la = &As[buf][wave*16][0];   // wave-uniform base + lane*16B
    unsigned short* lb = &Bs[buf][wave*16][0];
    #pragma unroll
    for (int g = 0; g < 2; ++g){
      GLOAD16(gA[g] + ko, la + g*2048);
      GLOAD16(gB[g] + ko, lb + g*2048);
    }
  };

  f32x4t acc[4][4] = {};
  const int fr = lane & 15;
  const int fq = lane >> 4;

  const int kt0 = (kz * NTfull) / KS;
  const int kt1 = ((kz + 1) * NTfull) / KS;
  const int NTl = kt1 - kt0;

  STAGE(0, kt0*32);

  int cur = 0;
  for (int t = 0; t < NTl; ++t){
    if (t + 1 < NTl){
      STAGE(cur ^ 1, (kt0 + t + 1)*32);
      SB0; asm volatile("s_waitcnt vmcnt(4)" ::: "memory");
    } else {
      SB0; asm volatile("s_waitcnt vmcnt(0)" ::: "memory");
    }
    __builtin_amdgcn_s_barrier();       // all waves' cur fills visible
    SB0;

    const unsigned short* Ab = &As[cur][0][0];
    const unsigned short* Bb = &Bs[cur][0][0];
    s16x8 bfr[4], afr[4];
    #pragma unroll
    for (int nf = 0; nf < 4; ++nf) bfr[nf] = lds_frag(Bb, wn + nf*16 + fr, fq*8);
    #pragma unroll
    for (int mf = 0; mf < 4; ++mf) afr[mf] = lds_frag(Ab, wm + mf*16 + fr, fq*8);
    #pragma unroll
    for (int mf = 0; mf < 4; ++mf)
      #pragma unroll
      for (int nf = 0; nf < 4; ++nf)
        acc[mf][nf] = __builtin_amdgcn_mfma_f32_16x16x32_bf16(afr[mf], bfr[nf], acc[mf][nf], 0, 0, 0);

    SB0;
    __builtin_amdgcn_s_barrier();       // readers done -> buf cur overwritable next iter
    SB0;
    cur ^= 1;
  }

  const int rbase = wm + fq*4;
  const int cbase = wn + fr;
  if (LAYER == 1){
    #pragma unroll
    for (int mf = 0; mf < 4; ++mf){
      #pragma unroll
      for (int nf = 0; nf < 4; ++nf){
        int c = cbase + nf*16;
        float bsv = bias[e*HDIM + n0 + c];
        #pragma unroll
        for (int j = 0; j < 4; ++j){
          int rr = rbase + mf*16 + j;
          float v = fmaxf(acc[mf][nf][j] + bsv, 0.f);
          __builtin_nontemporal_store((unsigned short)f2b(v),
              &Hout[(size_t)(tile*128 + rr)*HDIM + n0 + c]);
        }
      }
    }
  } else {
    #pragma unroll
    for (int mf = 0; mf < 4; ++mf){
      #pragma unroll
      for (int j = 0; j < 4; ++j){
        int rr = rbase + mf*16 + j;
        if (ts + rr < cnt){
          int tok = tokenBuf[rr];
          float w = wBuf[rr];
          #pragma unroll
          for (int nf = 0; nf < 4; ++nf){
            int c = cbase + nf*16;
            float v = acc[mf][nf][j];
            if (kz == 0) v += bias[e*DDIM + n0 + c];
            atomicAdd(out + (size_t)tok*DDIM + n0 + c, w * v);
          }
        }
      }
    }
  }
}

extern "C" void kernel_launch(void* const* d_in, const int* in_sizes, int n_in,
                              void* d_out, int out_size, void* d_ws, size_t ws_size,
                              hipStream_t stream){
  const float* x  = (const float*)d_in[0];
  const float* Wg = (const float*)d_in[1];
  const float* bg = (const float*)d_in[2];
  const float* W1 = (const float*)d_in[3];
  const float* b1 = (const float*)d_in[4];
  const float* W2 = (const float*)d_in[5];
  const float* b2 = (const float*)d_in[6];
  float* out = (float*)d_out;

  char* p = (char*)d_ws;
  int*   topk_e     = (int*)p;   p += (size_t)T_TOK*2*sizeof(int);
  float* topk_w     = (float*)p; p += (size_t)T_TOK*2*sizeof(float);
  int*   counts     = (int*)p;   p += 8*sizeof(int);
  int*   nTiles     = (int*)p;   p += 8*sizeof(int);
  int*   tileExpert = (int*)p;   p += 128*sizeof(int);
  int*   tileStart  = (int*)p;   p += 128*sizeof(int);
  int*   expertList = (int*)p;   p += (size_t)NEXP*T_TOK*sizeof(int);
  float* pairW      = (float*)p; p += (size_t)NEXP*T_TOK*sizeof(float);
  p = (char*)(((uintptr_t)p + 255) & ~(uintptr_t)255);
  unsigned short* xb = (unsigned short*)p;    // 8 MB
  p += (size_t)T_TOK*DDIM*sizeof(unsigned short);
  p = (char*)(((uintptr_t)p + 255) & ~(uintptr_t)255);
  unsigned short* Wtbuf = (unsigned short*)p; // 67 MB (W1t, then W2t)
  p += (size_t)NEXP*DDIM*HDIM*sizeof(unsigned short);
  p = (char*)(((uintptr_t)p + 255) & ~(uintptr_t)255);
  unsigned short* Hact = (unsigned short*)p;  // 75.5 MB

  hipMemsetAsync(d_out, 0, (size_t)T_TOK*DDIM*sizeof(float), stream);
  gate_kernel<<<T_TOK, 64, 0, stream>>>(x, Wg, bg, topk_e, topk_w, xb);
  route_count<<<NEXP, 256, 0, stream>>>(topk_e, topk_w, expertList, pairW, counts);
  plan_kernel<<<1, 1, 0, stream>>>(counts, nTiles, tileExpert, tileStart);

  transpose_w<<<dim3(HDIM/64, DDIM/64, NEXP), 256, 0, stream>>>(W1, Wtbuf, DDIM, HDIM);
  moe_gemm<1,1><<<dim3(MAXTILES*(HDIM/128), 1), 256, 0, stream>>>(
      xb, Wtbuf, b1, nTiles, tileExpert, tileStart, counts, expertList, pairW, Hact, nullptr);

  transpose_w<<<dim3(DDIM/64, HDIM/64, NEXP), 256, 0, stream>>>(W2, Wtbuf, HDIM, DDIM);
  moe_gemm<2,2><<<dim3(MAXTILES*(DDIM/128), 2), 256, 0, stream>>>(
      Hact, Wtbuf, b2, nTiles, tileExpert, tileStart, counts, expertList, pairW, nullptr, out);
}

// Round 19
// 373.426 us; speedup vs baseline: 1.1708x; 1.0289x over previous
//
#include <hip/hip_runtime.h>
#include <stdint.h>

#define T_TOK 4096
#define DDIM  1024
#define HDIM  4096
#define NEXP  8
#define MAXTILES 72                     // ceil(8192/128) + 8 experts of padding
#define G1_NWG (MAXTILES*(HDIM/128))    // 2304 GEMM1 blocks
#define TW_NWG 8192                     // transpose blocks (both layers: (K/64)*(N/64)*E)

typedef short s16x8  __attribute__((ext_vector_type(8)));
typedef float f32x4t __attribute__((ext_vector_type(4)));

#define GLOAD16(gp, lp) __builtin_amdgcn_global_load_lds( \
    (const __attribute__((address_space(1))) unsigned int*)(gp), \
    (__attribute__((address_space(3))) unsigned int*)(lp), 16, 0, 0)
#define SB0 __builtin_amdgcn_sched_barrier(0)

__device__ __forceinline__ unsigned short f2b(float f){
  unsigned int u = __float_as_uint(f);
  u += 0x7fffu + ((u >> 16) & 1u);   // RNE
  return (unsigned short)(u >> 16);
}

// BK=32 rows are 64 B (4 x 16B slots). Swizzle: slot ^= (row>>1)&3 (verified involution pair).
__device__ __forceinline__ s16x8 lds_frag(const unsigned short* base, int row, int colElem){
  int byte = row*64 + ((colElem*2) ^ (((row >> 1) & 3) << 4));
  return *(const s16x8*)((const char*)base + byte);
}

// ---------------- transpose body (device): W [K][N] fp32 -> Wt [N][K] bf16, one 64x64 tile ----
__device__ __forceinline__ void transpose_body(const float* __restrict__ W,
                                               unsigned short* __restrict__ Wt,
                                               int K, int N, int bid, int tid,
                                               unsigned short (*t)[72]){
  const int nb = N >> 6, kb = K >> 6;
  const int n0 = (bid % nb) * 64;
  const int k0 = ((bid / nb) % kb) * 64;
  const int e  = bid / (nb * kb);
  const float* Wb = W + (size_t)e*K*N;
  unsigned short* Wtb = Wt + (size_t)e*K*N;
  const int r  = tid >> 4;
  const int c4 = (tid & 15) * 4;
  #pragma unroll
  for (int i = 0; i < 4; ++i){
    int k = r + i*16;
    float4 v = *(const float4*)(Wb + (size_t)(k0+k)*N + n0 + c4);
    t[c4+0][k] = f2b(v.x); t[c4+1][k] = f2b(v.y);
    t[c4+2][k] = f2b(v.z); t[c4+3][k] = f2b(v.w);
  }
  __syncthreads();
  const int kk = (tid & 7) * 8;
  #pragma unroll
  for (int i = 0; i < 2; ++i){
    int n = (tid >> 3) + i*32;
    s16x8 v;
    #pragma unroll
    for (int j = 0; j < 8; ++j) v[j] = (short)t[n][kk+j];
    *(s16x8*)(Wtb + (size_t)(n0+n)*K + k0 + kk) = v;
  }
}

// ---------------- gate + x->bf16 conversion (fused) ----------------
__global__ void gate_kernel(const float* __restrict__ x, const float* __restrict__ Wg,
                            const float* __restrict__ bg,
                            int* __restrict__ topk_e, float* __restrict__ topk_w,
                            unsigned short* __restrict__ xb){
  const int t = blockIdx.x;
  const int lane = threadIdx.x;
  const float* xr = x + (size_t)t * DDIM;
  unsigned short* xbr = xb + (size_t)t * DDIM;
  float acc[NEXP];
  #pragma unroll
  for (int e = 0; e < NEXP; ++e) acc[e] = 0.f;
  #pragma unroll 4
  for (int it = 0; it < DDIM/64; ++it){
    int i = it*64 + lane;
    float xi = xr[i];
    xbr[i] = f2b(xi);
    const float4* wr = (const float4*)(Wg + (size_t)i * NEXP);
    float4 w0 = wr[0], w1 = wr[1];
    acc[0] += xi*w0.x; acc[1] += xi*w0.y; acc[2] += xi*w0.z; acc[3] += xi*w0.w;
    acc[4] += xi*w1.x; acc[5] += xi*w1.y; acc[6] += xi*w1.z; acc[7] += xi*w1.w;
  }
  #pragma unroll
  for (int e = 0; e < NEXP; ++e){
    float v = acc[e];
    #pragma unroll
    for (int off = 32; off > 0; off >>= 1) v += __shfl_xor(v, off, 64);
    acc[e] = v;
  }
  if (lane == 0){
    float l[NEXP], m = -1e30f;
    #pragma unroll
    for (int e = 0; e < NEXP; ++e){ l[e] = acc[e] + bg[e]; m = fmaxf(m, l[e]); }
    float p[NEXP], s = 0.f;
    #pragma unroll
    for (int e = 0; e < NEXP; ++e){ p[e] = expf(l[e] - m); s += p[e]; }
    float inv = 1.f / s;
    int a1 = 0; float v1 = -1.f;
    #pragma unroll
    for (int e = 0; e < NEXP; ++e){ p[e] *= inv; if (p[e] > v1){ v1 = p[e]; a1 = e; } }
    int a2 = -1; float v2 = -1.f;
    #pragma unroll
    for (int e = 0; e < NEXP; ++e){ if (e == a1) continue; if (p[e] > v2){ v2 = p[e]; a2 = e; } }
    topk_e[2*t]   = a1; topk_w[2*t]   = v1;
    topk_e[2*t+1] = a2; topk_w[2*t+1] = v2;
  }
}

// ---------------- route body (device): per-expert ordered compaction ----------------
__device__ __forceinline__ void route_body(const int* __restrict__ topk_e,
                                           const float* __restrict__ topk_w,
                                           int* __restrict__ expertList,
                                           float* __restrict__ pairW,
                                           int* __restrict__ counts,
                                           int e, int tid, int* pfx, int* base_s){
  if (tid == 0) *base_s = 0;
  __syncthreads();
  for (int c = 0; c < T_TOK/256; ++c){
    int t = c*256 + tid;
    int e0 = topk_e[2*t], e1 = topk_e[2*t+1];
    int sel = 0; float w = 0.f;
    if (e0 == e){ sel = 1; w = topk_w[2*t]; }
    else if (e1 == e){ sel = 1; w = topk_w[2*t+1]; }
    pfx[tid] = sel;
    __syncthreads();
    for (int off = 1; off < 256; off <<= 1){
      int v = (tid >= off) ? pfx[tid - off] : 0;
      __syncthreads();
      pfx[tid] += v;
      __syncthreads();
    }
    if (sel){
      int pos = *base_s + pfx[tid] - 1;
      expertList[e*T_TOK + pos] = t;
      pairW[e*T_TOK + pos] = w;
    }
    __syncthreads();
    if (tid == 0) *base_s += pfx[255];
    __syncthreads();
  }
  if (tid == 0) counts[e] = *base_s;
}

__global__ __launch_bounds__(256)
void route_count(const int* __restrict__ topk_e, const float* __restrict__ topk_w,
                 int* __restrict__ expertList, float* __restrict__ pairW,
                 int* __restrict__ counts){
  __shared__ int pfx[256];
  __shared__ int base_s;
  route_body(topk_e, topk_w, expertList, pairW, counts, blockIdx.x, threadIdx.x, pfx, &base_s);
}

// fused: blocks 0..7 route; blocks 8.. transpose W1 -> W1t
__global__ __launch_bounds__(256)
void route_t1_fused(const int* __restrict__ topk_e, const float* __restrict__ topk_w,
                    int* __restrict__ expertList, float* __restrict__ pairW,
                    int* __restrict__ counts,
                    const float* __restrict__ W1, unsigned short* __restrict__ W1t){
  __shared__ __align__(16) unsigned char smem[9216];
  if (blockIdx.x < NEXP){
    int* pfx = (int*)smem;
    int* base_s = (int*)(smem + 1024);
    route_body(topk_e, topk_w, expertList, pairW, counts, blockIdx.x, threadIdx.x, pfx, base_s);
  } else {
    transpose_body(W1, W1t, DDIM, HDIM, blockIdx.x - NEXP, threadIdx.x,
                   (unsigned short (*)[72])smem);
  }
}

__global__ void plan_kernel(const int* __restrict__ counts, int* __restrict__ nTiles,
                            int* __restrict__ tileExpert, int* __restrict__ tileStart){
  if (blockIdx.x != 0 || threadIdx.x != 0) return;
  int nt = 0;
  for (int e = 0; e < NEXP; ++e){
    int c = counts[e];
    int tcount = (c + 127) >> 7;
    for (int i = 0; i < tcount; ++i){ tileExpert[nt] = e; tileStart[nt] = i*128; ++nt; }
  }
  *nTiles = nt;
}

// ---------------- standalone transpose kernel (fallback path) ----------------
__global__ __launch_bounds__(256)
void transpose_w(const float* __restrict__ W, unsigned short* __restrict__ Wt,
                 int K, int N){
  __shared__ unsigned short t[64][72];
  const int bid = blockIdx.x + blockIdx.y*gridDim.x + blockIdx.z*gridDim.x*gridDim.y;
  // decode must match (K/64)*(N/64)*E linearization used by transpose_body
  transpose_body(W, Wt, K, N, bid, threadIdx.x, t);
}

// ------- grouped GEMM (session best): 128x128, BK=32, 4 waves, dbuf,
// 4 blocks/CU, top-placed counted vmcnt(4), T2 involution swizzle,
// n0-fastest decode + bijective XCD swizzle. -------
template<int LAYER, int KS>
__global__ __launch_bounds__(256, 4)
void moe_gemm(const unsigned short* __restrict__ Abf,
              const unsigned short* __restrict__ Wt,
              const float* __restrict__ bias,
              const int* __restrict__ nTilesPtr,
              const int* __restrict__ tileExpert,
              const int* __restrict__ tileStart,
              const int* __restrict__ counts,
              const int* __restrict__ expertList,
              const float* __restrict__ pairW,
              unsigned short* __restrict__ Hout,
              float* __restrict__ out)
{
  constexpr int KD = (LAYER == 1) ? DDIM : HDIM;
  constexpr int ND = (LAYER == 1) ? HDIM : DDIM;
  constexpr int NB = ND / 128;
  constexpr int NTfull = KD / 32;

  const int nwg = gridDim.x;
  const int b   = blockIdx.x;
  const int q8 = nwg >> 3, r8 = nwg & 7;
  const int xcd = b & 7, ii = b >> 3;
  const int lin = (xcd < r8 ? xcd*(q8+1) : r8*(q8+1) + (xcd-r8)*q8) + ii;
  const int tile = lin / NB;
  const int n0   = (lin % NB) * 128;
  const int kz   = blockIdx.y;

  if (tile >= *nTilesPtr) return;
  const int e   = tileExpert[tile];
  const int ts  = tileStart[tile];
  const int cnt = counts[e];
  const int tid  = threadIdx.x;
  const int lane = tid & 63;
  const int wave = tid >> 6;
  const int wm = (wave >> 1) * 64;
  const int wn = (wave & 1) * 64;

  __shared__ __align__(16) unsigned short As[2][128][32];
  __shared__ __align__(16) unsigned short Bs[2][128][32];
  __shared__ int   tokenBuf[128];
  __shared__ float wBuf[128];

  if (tid < 128){
    int pos = ts + tid;
    int tok = 0; float w = 0.f;
    if (pos < cnt){ tok = expertList[e*T_TOK + pos]; w = pairW[e*T_TOK + pos]; }
    tokenBuf[tid] = tok; wBuf[tid] = w;
  }
  __syncthreads();

  const int srow = tid >> 2;
  const int slot = (tid & 3) ^ ((tid >> 3) & 3);
  const int koff = slot * 8;
  const unsigned short* gA[2];
  const unsigned short* gB[2];
  #pragma unroll
  for (int g = 0; g < 2; ++g){
    const int row = g*64 + srow;
    if (LAYER == 1) gA[g] = Abf + (size_t)tokenBuf[row]*DDIM + koff;
    else            gA[g] = Abf + (size_t)(tile*128 + row)*HDIM + koff;
    gB[g] = Wt + ((size_t)e*ND + n0 + row)*KD + koff;
  }

  auto STAGE = [&](int buf, int ko){
    unsigned short* la = &As[buf][wave*16][0];
    unsigned short* lb = &Bs[buf][wave*16][0];
    #pragma unroll
    for (int g = 0; g < 2; ++g){
      GLOAD16(gA[g] + ko, la + g*2048);
      GLOAD16(gB[g] + ko, lb + g*2048);
    }
  };

  f32x4t acc[4][4] = {};
  const int fr = lane & 15;
  const int fq = lane >> 4;

  const int kt0 = (kz * NTfull) / KS;
  const int kt1 = ((kz + 1) * NTfull) / KS;
  const int NTl = kt1 - kt0;

  STAGE(0, kt0*32);

  int cur = 0;
  for (int t = 0; t < NTl; ++t){
    if (t + 1 < NTl){
      STAGE(cur ^ 1, (kt0 + t + 1)*32);
      SB0; asm volatile("s_waitcnt vmcnt(4)" ::: "memory");
    } else {
      SB0; asm volatile("s_waitcnt vmcnt(0)" ::: "memory");
    }
    __builtin_amdgcn_s_barrier();
    SB0;

    const unsigned short* Ab = &As[cur][0][0];
    const unsigned short* Bb = &Bs[cur][0][0];
    s16x8 bfr[4], afr[4];
    #pragma unroll
    for (int nf = 0; nf < 4; ++nf) bfr[nf] = lds_frag(Bb, wn + nf*16 + fr, fq*8);
    #pragma unroll
    for (int mf = 0; mf < 4; ++mf) afr[mf] = lds_frag(Ab, wm + mf*16 + fr, fq*8);
    #pragma unroll
    for (int mf = 0; mf < 4; ++mf)
      #pragma unroll
      for (int nf = 0; nf < 4; ++nf)
        acc[mf][nf] = __builtin_amdgcn_mfma_f32_16x16x32_bf16(afr[mf], bfr[nf], acc[mf][nf], 0, 0, 0);

    SB0;
    __builtin_amdgcn_s_barrier();
    SB0;
    cur ^= 1;
  }

  const int rbase = wm + fq*4;
  const int cbase = wn + fr;
  if (LAYER == 1){
    #pragma unroll
    for (int mf = 0; mf < 4; ++mf){
      #pragma unroll
      for (int nf = 0; nf < 4; ++nf){
        int c = cbase + nf*16;
        float bsv = bias[e*HDIM + n0 + c];
        #pragma unroll
        for (int j = 0; j < 4; ++j){
          int rr = rbase + mf*16 + j;
          float v = fmaxf(acc[mf][nf][j] + bsv, 0.f);
          __builtin_nontemporal_store((unsigned short)f2b(v),
              &Hout[(size_t)(tile*128 + rr)*HDIM + n0 + c]);
        }
      }
    }
  } else {
    #pragma unroll
    for (int mf = 0; mf < 4; ++mf){
      #pragma unroll
      for (int j = 0; j < 4; ++j){
        int rr = rbase + mf*16 + j;
        if (ts + rr < cnt){
          int tok = tokenBuf[rr];
          float w = wBuf[rr];
          #pragma unroll
          for (int nf = 0; nf < 4; ++nf){
            int c = cbase + nf*16;
            float v = acc[mf][nf][j];
            if (kz == 0) v += bias[e*DDIM + n0 + c];
            atomicAdd(out + (size_t)tok*DDIM + n0 + c, w * v);
          }
        }
      }
    }
  }
}

// ------- fused GEMM1 + transpose(W2): blocks [0,G1_NWG) = GEMM1; rest transpose -------
__global__ __launch_bounds__(256, 4)
void gemm1_t2_fused(const unsigned short* __restrict__ Abf,
                    const unsigned short* __restrict__ Wt,     // W1t
                    const float* __restrict__ bias,            // b1
                    const int* __restrict__ nTilesPtr,
                    const int* __restrict__ tileExpert,
                    const int* __restrict__ tileStart,
                    const int* __restrict__ counts,
                    const int* __restrict__ expertList,
                    unsigned short* __restrict__ Hout,
                    const float* __restrict__ W2,
                    unsigned short* __restrict__ W2t)
{
  __shared__ __align__(16) unsigned char smem[33792];
  if (blockIdx.x >= G1_NWG){
    transpose_body(W2, W2t, HDIM, DDIM, blockIdx.x - G1_NWG, threadIdx.x,
                   (unsigned short (*)[72])smem);
    return;
  }
  // ---- GEMM1 body (LAYER=1, KS=1), smem carved from the union block ----
  auto As = (unsigned short (*)[128][32])smem;            // As[2][128][32]
  auto Bs = (unsigned short (*)[128][32])(smem + 16384);
  int* tokenBuf = (int*)(smem + 32768);                   // 512 B

  constexpr int KD = DDIM, ND = HDIM;
  constexpr int NB = ND / 128;
  constexpr int NT = KD / 32;

  const int nwg = G1_NWG;                // swizzle over the GEMM sub-grid only
  const int b   = blockIdx.x;
  const int q8 = nwg >> 3, r8 = nwg & 7;
  const int xcd = b & 7, ii = b >> 3;
  const int lin = (xcd < r8 ? xcd*(q8+1) : r8*(q8+1) + (xcd-r8)*q8) + ii;
  const int tile = lin / NB;
  const int n0   = (lin % NB) * 128;

  if (tile >= *nTilesPtr) return;
  const int e   = tileExpert[tile];
  const int ts  = tileStart[tile];
  const int cnt = counts[e];
  const int tid  = threadIdx.x;
  const int lane = tid & 63;
  const int wave = tid >> 6;
  const int wm = (wave >> 1) * 64;
  const int wn = (wave & 1) * 64;

  if (tid < 128){
    int pos = ts + tid;
    int tok = 0;
    if (pos < cnt) tok = expertList[e*T_TOK + pos];
    tokenBuf[tid] = tok;
  }
  __syncthreads();

  const int srow = tid >> 2;
  const int slot = (tid & 3) ^ ((tid >> 3) & 3);
  const int koff = slot * 8;
  const unsigned short* gA[2];
  const unsigned short* gB[2];
  #pragma unroll
  for (int g = 0; g < 2; ++g){
    const int row = g*64 + srow;
    gA[g] = Abf + (size_t)tokenBuf[row]*DDIM + koff;
    gB[g] = Wt + ((size_t)e*ND + n0 + row)*KD + koff;
  }

  auto STAGE = [&](int buf, int ko){
    unsigned short* la = &As[buf][wave*16][0];
    unsigned short* lb = &Bs[buf][wave*16][0];
    #pragma unroll
    for (int g = 0; g < 2; ++g){
      GLOAD16(gA[g] + ko, la + g*2048);
      GLOAD16(gB[g] + ko, lb + g*2048);
    }
  };

  f32x4t acc[4][4] = {};
  const int fr = lane & 15;
  const int fq = lane >> 4;

  STAGE(0, 0);

  int cur = 0;
  for (int t = 0; t < NT; ++t){
    if (t + 1 < NT){
      STAGE(cur ^ 1, (t + 1)*32);
      SB0; asm volatile("s_waitcnt vmcnt(4)" ::: "memory");
    } else {
      SB0; asm volatile("s_waitcnt vmcnt(0)" ::: "memory");
    }
    __builtin_amdgcn_s_barrier();
    SB0;

    const unsigned short* Ab = &As[cur][0][0];
    const unsigned short* Bb = &Bs[cur][0][0];
    s16x8 bfr[4], afr[4];
    #pragma unroll
    for (int nf = 0; nf < 4; ++nf) bfr[nf] = lds_frag(Bb, wn + nf*16 + fr, fq*8);
    #pragma unroll
    for (int mf = 0; mf < 4; ++mf) afr[mf] = lds_frag(Ab, wm + mf*16 + fr, fq*8);
    #pragma unroll
    for (int mf = 0; mf < 4; ++mf)
      #pragma unroll
      for (int nf = 0; nf < 4; ++nf)
        acc[mf][nf] = __builtin_amdgcn_mfma_f32_16x16x32_bf16(afr[mf], bfr[nf], acc[mf][nf], 0, 0, 0);

    SB0;
    __builtin_amdgcn_s_barrier();
    SB0;
    cur ^= 1;
  }

  const int rbase = wm + fq*4;
  const int cbase = wn + fr;
  #pragma unroll
  for (int mf = 0; mf < 4; ++mf){
    #pragma unroll
    for (int nf = 0; nf < 4; ++nf){
      int c = cbase + nf*16;
      float bsv = bias[e*HDIM + n0 + c];
      #pragma unroll
      for (int j = 0; j < 4; ++j){
        int rr = rbase + mf*16 + j;
        float v = fmaxf(acc[mf][nf][j] + bsv, 0.f);
        __builtin_nontemporal_store((unsigned short)f2b(v),
            &Hout[(size_t)(tile*128 + rr)*HDIM + n0 + c]);
      }
    }
  }
}

extern "C" void kernel_launch(void* const* d_in, const int* in_sizes, int n_in,
                              void* d_out, int out_size, void* d_ws, size_t ws_size,
                              hipStream_t stream){
  const float* x  = (const float*)d_in[0];
  const float* Wg = (const float*)d_in[1];
  const float* bg = (const float*)d_in[2];
  const float* W1 = (const float*)d_in[3];
  const float* b1 = (const float*)d_in[4];
  const float* W2 = (const float*)d_in[5];
  const float* b2 = (const float*)d_in[6];
  float* out = (float*)d_out;

  const size_t WB = (size_t)NEXP*DDIM*HDIM*sizeof(unsigned short);      // 67,108,864
  const size_t HB = (size_t)MAXTILES*128*HDIM*sizeof(unsigned short);   // 75,497,472

  char* p = (char*)d_ws;
  int*   topk_e     = (int*)p;   p += (size_t)T_TOK*2*sizeof(int);
  float* topk_w     = (float*)p; p += (size_t)T_TOK*2*sizeof(float);
  int*   counts     = (int*)p;   p += 8*sizeof(int);
  int*   nTiles     = (int*)p;   p += 8*sizeof(int);
  int*   tileExpert = (int*)p;   p += 128*sizeof(int);
  int*   tileStart  = (int*)p;   p += 128*sizeof(int);
  int*   expertList = (int*)p;   p += (size_t)NEXP*T_TOK*sizeof(int);
  float* pairW      = (float*)p; p += (size_t)NEXP*T_TOK*sizeof(float);
  p = (char*)(((uintptr_t)p + 255) & ~(uintptr_t)255);
  unsigned short* xb = (unsigned short*)p;
  p += (size_t)T_TOK*DDIM*sizeof(unsigned short);
  p = (char*)(((uintptr_t)p + 255) & ~(uintptr_t)255);
  unsigned short* W1t = (unsigned short*)p; p += WB;
  p = (char*)(((uintptr_t)p + 255) & ~(uintptr_t)255);

  // separate W2t only if workspace permits (deterministic: ws_size fixed across calls)
  const size_t used = (size_t)(p - (char*)d_ws);
  const bool sep = (used + WB + 256 + HB + 256) <= ws_size;
  unsigned short* W2t;
  if (sep){
    W2t = (unsigned short*)p; p += WB;
    p = (char*)(((uintptr_t)p + 255) & ~(uintptr_t)255);
  } else {
    W2t = W1t;   // fallback: shared buffer, serialized transposes (R18 path)
  }
  unsigned short* Hact = (unsigned short*)p;

  hipMemsetAsync(d_out, 0, (size_t)T_TOK*DDIM*sizeof(float), stream);
  gate_kernel<<<T_TOK, 64, 0, stream>>>(x, Wg, bg, topk_e, topk_w, xb);

  if (sep){
    // transpose(W1) hides under route; transpose(W2) hides under GEMM1
    route_t1_fused<<<NEXP + TW_NWG, 256, 0, stream>>>(
        topk_e, topk_w, expertList, pairW, counts, W1, W1t);
    plan_kernel<<<1, 1, 0, stream>>>(counts, nTiles, tileExpert, tileStart);
    gemm1_t2_fused<<<G1_NWG + TW_NWG, 256, 0, stream>>>(
        xb, W1t, b1, nTiles, tileExpert, tileStart, counts, expertList, Hact, W2, W2t);
    moe_gemm<2,2><<<dim3(MAXTILES*(DDIM/128), 2), 256, 0, stream>>>(
        Hact, W2t, b2, nTiles, tileExpert, tileStart, counts, expertList, pairW, nullptr, out);
  } else {
    route_count<<<NEXP, 256, 0, stream>>>(topk_e, topk_w, expertList, pairW, counts);
    plan_kernel<<<1, 1, 0, stream>>>(counts, nTiles, tileExpert, tileStart);
    transpose_w<<<dim3(HDIM/64, DDIM/64, NEXP), 256, 0, stream>>>(W1, W1t, DDIM, HDIM);
    moe_gemm<1,1><<<dim3(G1_NWG, 1), 256, 0, stream>>>(
        xb, W1t, b1, nTiles, tileExpert, tileStart, counts, expertList, pairW, Hact, nullptr);
    transpose_w<<<dim3(DDIM/64, HDIM/64, NEXP), 256, 0, stream>>>(W2, W1t, HDIM, DDIM);
    moe_gemm<2,2><<<dim3(MAXTILES*(DDIM/128), 2), 256, 0, stream>>>(
        Hact, W1t, b2, nTiles, tileExpert, tileStart, counts, expertList, pairW, nullptr, out);
  }
}